// Round 4
// baseline (292.000 us; speedup 1.0000x reference)
//
#include <hip/hip_runtime.h>

// LinearAttention: N=8, L=S=4096, H=8, D=M=64, fp32.
// phase1 (16 s-splits): KVp[sp][nh][d][m] = sum_s phi(K)[s,d]*mask[s]*V[s,m]; Ksump likewise
// reduce: KVt = sum_sp KVp ; Ksum = sum_sp Ksump
// phase2: out[n,l,h,m] = (phi(Q)[l,:]·KVt[:,m]) / (phi(Q)[l,:]·Ksum + eps)

#define SLEN 4096
#define LLEN 4096
#define NHTOT 64      // N*H
#define HD   512      // H*D row stride in elements
#define NSPLIT 16
#define EPSF 1e-6f

__device__ __forceinline__ float phi(float x) {
    return x > 0.0f ? x + 1.0f : __expf(x);
}

__device__ __forceinline__ void fma4(float4& a, float s, const float4& b) {
    a.x = fmaf(s, b.x, a.x);
    a.y = fmaf(s, b.y, a.y);
    a.z = fmaf(s, b.z, a.z);
    a.w = fmaf(s, b.w, a.w);
}

__device__ __forceinline__ void add4(float4& a, const float4& b) {
    a.x += b.x; a.y += b.y; a.z += b.z; a.w += b.w;
}

// ---------------- Phase 1: per-split KV partials ----------------
// grid (NSPLIT, 64), block 256 = 4 waves. Block: 256 s-rows in 4 tiles of 64.
// Each wave computes the FULL 64x64 tile (8x8 per lane) over its 16-s quarter
// -> 4 b128 LDS reads per 64 FMA-instructions (2x better than 4x4 tiling).
// Epilogue: 4-barrier LDS tree reduce across the 4 waves.
__global__ __launch_bounds__(256)
void la_phase1(const float* __restrict__ Kg, const float* __restrict__ Vg,
               const float* __restrict__ maskg,
               float* __restrict__ KVp, float* __restrict__ Ksump) {
    __shared__ float lds[9472];      // 37.9 KB -> 4 blocks/CU
    float* kb  = lds;                // [64][68] phi(K)*mask (pad 68: 2-way max on reads)
    float* vb  = lds + 4352;         // [64][64] V
    float* ksb = lds + 8448;         // [16][64] ksum partials
    float* Red0 = lds;               // epilogue reuse: [64][64]
    float* Red1 = lds + 4096;        // epilogue reuse: [64][64]

    const int tid  = threadIdx.x;
    const int w    = tid >> 6;
    const int lane = tid & 63;
    const int nh   = blockIdx.y;
    const int n    = nh >> 3;
    const int h    = nh & 7;
    const int sp   = blockIdx.x;

    // staging role: 16 rows x 16 chunks per pass
    const int sr = tid >> 4;          // 0..15
    const int c4 = (tid & 15) * 4;    // float column
    // compute role: 8x8 per-lane tile covering the full 64x64
    const int d0 = (lane & 7) * 8;
    const int m0 = (lane >> 3) * 8;

    const size_t base = (size_t)n * SLEN * HD + (size_t)h * 64;
    const float* mrow = maskg + (size_t)n * SLEN;
    const int sblock = sp * 256;

    float4 acc[8][2];
    #pragma unroll
    for (int i = 0; i < 8; ++i) {
        acc[i][0] = make_float4(0.f, 0.f, 0.f, 0.f);
        acc[i][1] = make_float4(0.f, 0.f, 0.f, 0.f);
    }
    float4 ksp = make_float4(0.f, 0.f, 0.f, 0.f);

    for (int t = 0; t < 4; ++t) {
        const int srow0 = sblock + t * 64;
        __syncthreads();   // previous tile's reads done before overwrite
        #pragma unroll
        for (int u = 0; u < 4; ++u) {
            const int row = sr + u * 16;
            const int s   = srow0 + row;
            const size_t g = base + (size_t)s * HD + c4;
            float4 kf = *(const float4*)(Kg + g);
            const float mm = mrow[s];
            kf.x = phi(kf.x) * mm;
            kf.y = phi(kf.y) * mm;
            kf.z = phi(kf.z) * mm;
            kf.w = phi(kf.w) * mm;
            ksp.x += kf.x; ksp.y += kf.y; ksp.z += kf.z; ksp.w += kf.w;
            *(float4*)&kb[row * 68 + c4] = kf;
            *(float4*)&vb[row * 64 + c4] = *(const float4*)(Vg + g);
        }
        __syncthreads();
        // wave w handles s = w*16 .. w*16+15 of this 64-row tile
        #pragma unroll
        for (int j = 0; j < 16; ++j) {
            const int s = w * 16 + j;
            const float4 ka = *(const float4*)&kb[s * 68 + d0];
            const float4 kc = *(const float4*)&kb[s * 68 + d0 + 4];
            const float4 va = *(const float4*)&vb[s * 64 + m0];
            const float4 vc = *(const float4*)&vb[s * 64 + m0 + 4];
            const float kk[8] = {ka.x, ka.y, ka.z, ka.w, kc.x, kc.y, kc.z, kc.w};
            #pragma unroll
            for (int di = 0; di < 8; ++di) {
                fma4(acc[di][0], kk[di], va);
                fma4(acc[di][1], kk[di], vc);
            }
        }
    }

    // ---------------- epilogue: cross-wave tree reduce ----------------
    __syncthreads();                      // all compute reads of kb/vb done
    if (w == 2) {
        #pragma unroll
        for (int di = 0; di < 8; ++di) {
            *(float4*)&Red0[(d0 + di) * 64 + m0]     = acc[di][0];
            *(float4*)&Red0[(d0 + di) * 64 + m0 + 4] = acc[di][1];
        }
    }
    if (w == 3) {
        #pragma unroll
        for (int di = 0; di < 8; ++di) {
            *(float4*)&Red1[(d0 + di) * 64 + m0]     = acc[di][0];
            *(float4*)&Red1[(d0 + di) * 64 + m0 + 4] = acc[di][1];
        }
    }
    *(float4*)&ksb[sr * 64 + c4] = ksp;   // disjoint region
    __syncthreads();
    if (w == 0) {
        #pragma unroll
        for (int di = 0; di < 8; ++di) {
            const float4 a = *(const float4*)&Red0[(d0 + di) * 64 + m0];
            const float4 b = *(const float4*)&Red0[(d0 + di) * 64 + m0 + 4];
            add4(acc[di][0], a);
            add4(acc[di][1], b);
        }
    }
    if (w == 1) {
        #pragma unroll
        for (int di = 0; di < 8; ++di) {
            const float4 a = *(const float4*)&Red1[(d0 + di) * 64 + m0];
            const float4 b = *(const float4*)&Red1[(d0 + di) * 64 + m0 + 4];
            add4(acc[di][0], a);
            add4(acc[di][1], b);
        }
    }
    if (tid < 64) {
        float ssum = 0.f;
        #pragma unroll
        for (int r = 0; r < 16; ++r) ssum += ksb[r * 64 + tid];
        Ksump[((size_t)sp * NHTOT + nh) * 64 + tid] = ssum;
    }
    __syncthreads();
    if (w == 1) {
        #pragma unroll
        for (int di = 0; di < 8; ++di) {
            *(float4*)&Red0[(d0 + di) * 64 + m0]     = acc[di][0];
            *(float4*)&Red0[(d0 + di) * 64 + m0 + 4] = acc[di][1];
        }
    }
    __syncthreads();
    if (w == 0) {
        float* outp = KVp + ((size_t)sp * NHTOT + nh) * 4096;
        #pragma unroll
        for (int di = 0; di < 8; ++di) {
            const float4 a = *(const float4*)&Red0[(d0 + di) * 64 + m0];
            const float4 b = *(const float4*)&Red0[(d0 + di) * 64 + m0 + 4];
            float4 o0 = acc[di][0], o1 = acc[di][1];
            add4(o0, a);
            add4(o1, b);
            *(float4*)&outp[(d0 + di) * 64 + m0]     = o0;
            *(float4*)&outp[(d0 + di) * 64 + m0 + 4] = o1;
        }
    }
}

// ---------------- Reduce: sum the 16 split partials (wide grid) ----------------
// grid 257, block 256. Blocks 0..255: one float4 of KVt per thread. Block 256: Ksum.
__global__ __launch_bounds__(256)
void la_reduce(const float* __restrict__ KVp, const float* __restrict__ Ksump,
               float* __restrict__ KVt, float* __restrict__ Ksum) {
    const int tid = threadIdx.x;
    if (blockIdx.x < 256) {
        const size_t f = ((size_t)blockIdx.x * 256 + tid) * 4;   // over 64*4096 floats
        float4 a = make_float4(0.f, 0.f, 0.f, 0.f);
        #pragma unroll
        for (int sp = 0; sp < NSPLIT; ++sp)
            add4(a, *(const float4*)&KVp[(size_t)sp * NHTOT * 4096 + f]);
        *(float4*)&KVt[f] = a;
    } else {
        #pragma unroll
        for (int j = 0; j < 4; ++j) {
            const int c = (j * 256 + tid) * 4;   // over 64*64 floats
            float4 a = make_float4(0.f, 0.f, 0.f, 0.f);
            #pragma unroll
            for (int sp = 0; sp < NSPLIT; ++sp)
                add4(a, *(const float4*)&Ksump[sp * NHTOT * 64 + c]);
            *(float4*)&Ksum[c] = a;
        }
    }
}

// ---------------- Phase 2: out = phi(Q) @ KVt, normalized ----------------
// grid (L/256, 64), block 256 = 4 waves, 256 rows x 64 m per block.
// Per-lane tile 8 rows x 8 m (0.066 LDS instr / lane-MAC). Q staged in two
// 32-d halves (256x32, XOR-swizzled chunks: conflict-free, no padding).
__global__ __launch_bounds__(256)
void la_phase2(const float* __restrict__ Qg, const float* __restrict__ KVt,
               const float* __restrict__ Ksum, float* __restrict__ Og) {
    __shared__ float Qs[256 * 32];   // 32 KB (chunk-swizzled)
    __shared__ float KVs[4096];      // 16 KB [d][m]
    __shared__ float KSs[64];        // total 48.3 KB -> 3 blocks/CU

    const int tid = threadIdx.x;
    const int nh  = blockIdx.y;
    const int n   = nh >> 3;
    const int h   = nh & 7;
    const int lbase = blockIdx.x * 256;

    // ---- stage KV + Ksum ----
    #pragma unroll
    for (int j = 0; j < 4; ++j) {
        const int f = (j * 256 + tid) * 4;
        *(float4*)&KVs[f] = *(const float4*)&KVt[(size_t)nh * 4096 + f];
    }
    if (tid < 16) *(float4*)&KSs[tid * 4] = *(const float4*)&Ksum[nh * 64 + tid * 4];

    const int w    = tid >> 6;        // wave row band: w*64
    const int lane = tid & 63;
    const int ry   = lane >> 3;       // 0..7
    const int tx   = lane & 7;        // m-group
    const int m0   = tx * 8;
    const int rowb = w * 64 + ry;     // thread rows: rowb + 8*i

    // staging role
    const int sc   = tid & 7;         // 4-float chunk within 32-d half
    const int srow = tid >> 3;        // 0..31, 8 passes

    float4 acc[8][2];
    float  den[8];
    #pragma unroll
    for (int i = 0; i < 8; ++i) {
        acc[i][0] = make_float4(0.f, 0.f, 0.f, 0.f);
        acc[i][1] = make_float4(0.f, 0.f, 0.f, 0.f);
        den[i] = 0.f;
    }

    for (int half = 0; half < 2; ++half) {
        __syncthreads();   // prev-half reads done (and KVs staged, 1st iter)
        #pragma unroll
        for (int p = 0; p < 8; ++p) {
            const int row = srow + p * 32;
            float4 q = *(const float4*)&Qg[((size_t)(n * LLEN + lbase + row) * 8 + h) * 64
                                           + half * 32 + sc * 4];
            q.x = phi(q.x); q.y = phi(q.y); q.z = phi(q.z); q.w = phi(q.w);
            const int chunk = (sc + row) & 7;      // XOR-rotate swizzle
            *(float4*)&Qs[row * 32 + chunk * 4] = q;
        }
        __syncthreads();
        #pragma unroll
        for (int dq = 0; dq < 8; ++dq) {
            const float4 ks = *(const float4*)&KSs[(half * 8 + dq) * 4];
            float4 q4[8];
            #pragma unroll
            for (int i = 0; i < 8; ++i) {
                const int row = rowb + 8 * i;
                const int chunk = (dq + row) & 7;
                q4[i] = *(const float4*)&Qs[row * 32 + chunk * 4];
            }
            #pragma unroll
            for (int i = 0; i < 8; ++i) {
                den[i] = fmaf(q4[i].x, ks.x, den[i]);
                den[i] = fmaf(q4[i].y, ks.y, den[i]);
                den[i] = fmaf(q4[i].z, ks.z, den[i]);
                den[i] = fmaf(q4[i].w, ks.w, den[i]);
            }
            #pragma unroll
            for (int dk = 0; dk < 4; ++dk) {
                const int d = half * 32 + dq * 4 + dk;
                const float4 kv0 = *(const float4*)&KVs[d * 64 + m0];
                const float4 kv1 = *(const float4*)&KVs[d * 64 + m0 + 4];
                #pragma unroll
                for (int i = 0; i < 8; ++i) {
                    const float qs = (&q4[i].x)[dk];
                    fma4(acc[i][0], qs, kv0);
                    fma4(acc[i][1], qs, kv1);
                }
            }
        }
    }

    // ---- normalize + store ----
    #pragma unroll
    for (int i = 0; i < 8; ++i) {
        const int l = lbase + rowb + 8 * i;
        const float z = 1.0f / (den[i] + EPSF);
        float4 o0 = acc[i][0], o1 = acc[i][1];
        o0.x *= z; o0.y *= z; o0.z *= z; o0.w *= z;
        o1.x *= z; o1.y *= z; o1.z *= z; o1.w *= z;
        float* op = Og + ((size_t)(n * LLEN + l) * 8 + h) * 64 + m0;
        *(float4*)&op[0] = o0;
        *(float4*)&op[4] = o1;
    }
}

extern "C" void kernel_launch(void* const* d_in, const int* in_sizes, int n_in,
                              void* d_out, int out_size, void* d_ws, size_t ws_size,
                              hipStream_t stream) {
    const float* Q    = (const float*)d_in[0];
    const float* K    = (const float*)d_in[1];
    const float* V    = (const float*)d_in[2];
    const float* mask = (const float*)d_in[3];
    float* out = (float*)d_out;

    float* KVp   = (float*)d_ws;                                  // [16][64][4096] = 16.8 MB
    float* Ksump = KVp + (size_t)NSPLIT * NHTOT * 4096;           // [16][64][64]
    float* KVt   = Ksump + (size_t)NSPLIT * NHTOT * 64;           // [64][4096]
    float* Ksum  = KVt + (size_t)NHTOT * 4096;                    // [64][64]
    // every ws element read is written first (no memset needed)

    dim3 g1(NSPLIT, NHTOT);
    la_phase1<<<g1, 256, 0, stream>>>(K, V, mask, KVp, Ksump);

    la_reduce<<<257, 256, 0, stream>>>(KVp, Ksump, KVt, Ksum);

    dim3 g2(LLEN / 256, NHTOT);
    la_phase2<<<g2, 256, 0, stream>>>(Q, KVt, Ksum, out);
}